// Round 6
// baseline (593.978 us; speedup 1.0000x reference)
//
#include <hip/hip_runtime.h>
#include <math.h>

#define NN 100000
#define NE 3200000
#define INF_ 256
#define NH 8
#define OF 64
#define EF 64
#define NT 8

#define BSH 7                  // log2(nodes per bucket)
#define BNODES 128             // nodes per bucket
#define NB 782                 // ceil(NN/128)
#define SPLIT 4                // sub-blocks per bucket in k_bucket_sum / k_out
#define EPB 4096               // edges per k_count/k_partition block

typedef unsigned long long u64;

// ws layout (float units). Exact prefix-sum bucket addressing: part64 is NE u64 recs
// (sj|et|dl|eid), bucket b occupies [base[b], base[b+1]). Peak ws = 35.2 MB (< the
// 36.85 MB the round-0 layout proved available).
static constexpr size_t WS_AT     = 0;                          // 4096
static constexpr size_t WS_EE     = 4096;                       // 64
static constexpr size_t WS_EL     = 4160;                       // NN*8
static constexpr size_t WS_ERS    = WS_EL + (size_t)NN * 8;     // NN*16
static constexpr size_t WS_CCNT   = WS_ERS + (size_t)NN * 16;   // NB   (counts)
static constexpr size_t WS_BASE   = WS_CCNT + NB;               // NB+1 (prefix sums)
static constexpr size_t WS_CUR    = WS_BASE + NB + 1;           // NB   (scatter cursors)
static constexpr size_t WS_PART64 = ((WS_CUR + NB + 1) & ~(size_t)1); // NE u64 (8B-aligned)

// K1a: At[c][i] = sum_o W_fc[i, h*64+o]*attn[h,o]; c<8->attn_l, c>=8->attn_r. Zeroes ccnt.
__global__ __launch_bounds__(256) void k_prep_A(const float* __restrict__ W_fc,
                                                const float* __restrict__ attn_l,
                                                const float* __restrict__ attn_r,
                                                float* __restrict__ At,
                                                unsigned* __restrict__ ccnt) {
    int t = blockIdx.x * 256 + threadIdx.x;   // 0..4095
    if (t < NB) ccnt[t] = 0u;
    int c = t >> 8;
    int i = t & 255;
    int h = c & 7;
    const float* attn = (c < 8) ? attn_l : attn_r;
    const float* wrow = W_fc + (size_t)i * (NH * OF) + h * OF;
    const float* arow = attn + h * OF;
    float acc = 0.f;
#pragma unroll 8
    for (int o = 0; o < OF; ++o) acc += wrow[o] * arow[o];
    At[c * INF_ + i] = acc;
}

// K1b: ee_tab[t][h]
__global__ __launch_bounds__(512) void k_prep_ee(const float* __restrict__ edge_emb,
                                                 const float* __restrict__ W_e,
                                                 const float* __restrict__ attn_e,
                                                 float* __restrict__ ee_tab) {
    __shared__ float B[EF][NH];
    int t = threadIdx.x;
    int g = t >> 3, h = t & 7;
    const float* wrow = W_e + (size_t)g * (NH * EF) + h * EF;
    const float* arow = attn_e + h * EF;
    float acc = 0.f;
#pragma unroll 8
    for (int f = 0; f < EF; ++f) acc += wrow[f] * arow[f];
    B[g][h] = acc;
    __syncthreads();
    if (t < NT * NH) {
        int tt = t >> 3, hh = t & 7;
        float a = 0.f;
#pragma unroll 8
        for (int g2 = 0; g2 < EF; ++g2) a += edge_emb[tt * EF + g2] * B[g2][hh];
        ee_tab[tt * NH + hh] = a;
    }
}

// K2: el[n][h], ers[n][0..7]=er, ers[n][8..15]=0 (s accumulator init)
__global__ __launch_bounds__(256) void k_node(const float* __restrict__ feat,
                                              const float* __restrict__ At,
                                              float* __restrict__ el,
                                              float* __restrict__ ers) {
    int n = blockIdx.x * 256 + threadIdx.x;
    if (n >= NN) return;
    const float4* f4 = (const float4*)(feat + (size_t)n * INF_);
    const float4* A4 = (const float4*)At;
    float acc[16];
#pragma unroll
    for (int c = 0; c < 16; ++c) acc[c] = 0.f;
    for (int iq = 0; iq < INF_ / 4; ++iq) {
        float4 f = f4[iq];
#pragma unroll
        for (int c = 0; c < 16; ++c) {
            float4 a = A4[c * 64 + iq];
            acc[c] += f.x * a.x + f.y * a.y + f.z * a.z + f.w * a.w;
        }
    }
    float4* e4 = (float4*)(el + (size_t)n * 8);
    e4[0] = make_float4(acc[0], acc[1], acc[2], acc[3]);
    e4[1] = make_float4(acc[4], acc[5], acc[6], acc[7]);
    float4* r4 = (float4*)(ers + (size_t)n * 16);
    r4[0] = make_float4(acc[8], acc[9], acc[10], acc[11]);
    r4[1] = make_float4(acc[12], acc[13], acc[14], acc[15]);
    r4[2] = make_float4(0.f, 0.f, 0.f, 0.f);
    r4[3] = make_float4(0.f, 0.f, 0.f, 0.f);
}

// K3a-count: per-bucket edge counts (LDS hist -> one global atomic per bucket per block).
__global__ __launch_bounds__(256) void k_count(const int* __restrict__ dst,
                                               unsigned* __restrict__ ccnt) {
    __shared__ unsigned hist[NB];
    int tid = threadIdx.x;
    size_t base = (size_t)blockIdx.x * EPB;
    for (int i = tid; i < NB; i += 256) hist[i] = 0u;
    __syncthreads();
#pragma unroll
    for (int k = 0; k < 16; ++k) {
        size_t j = base + (size_t)k * 256 + tid;
        if (j < NE) atomicAdd(&hist[dst[j] >> BSH], 1u);
    }
    __syncthreads();
    for (int i = tid; i < NB; i += 256) {
        unsigned h = hist[i];
        if (h) atomicAdd(ccnt + i, h);
    }
}

// K3a-scan: exclusive prefix over 782 counts (1 block; thread-0 serial in LDS).
// bases -> base[0..NB] (base[NB]=NE), cursors initialized to base.
__global__ __launch_bounds__(256) void k_scan(const unsigned* __restrict__ ccnt,
                                              unsigned* __restrict__ base,
                                              unsigned* __restrict__ cur) {
    __shared__ unsigned v[NB];
    int t = threadIdx.x;
    for (int i = t; i < NB; i += 256) v[i] = ccnt[i];
    __syncthreads();
    if (t == 0) {
        unsigned acc = 0;
        for (int i = 0; i < NB; ++i) { unsigned c = v[i]; v[i] = acc; acc += c; }
    }
    __syncthreads();
    for (int i = t; i < NB; i += 256) { base[i] = v[i]; cur[i] = v[i]; }
    if (t == 0) base[NB] = NE;
}

// K3a-scatter: u64 recs {sj[0:17) | et[17:20) | dl[20:27) | eid[27:49)} into exact
// per-bucket regions. Per-block LDS hist -> one global atomicAdd reservation per
// bucket -> LDS-cursor scatter. Capacity is exact: no clamp, no dropped edges.
__global__ __launch_bounds__(256) void k_partition(const int* __restrict__ src,
                                                   const int* __restrict__ dst,
                                                   const int* __restrict__ etype,
                                                   unsigned* __restrict__ cur,
                                                   u64* __restrict__ part64) {
    __shared__ unsigned hist[NB];
    __shared__ unsigned curs[NB];
    int tid = threadIdx.x;
    size_t base = (size_t)blockIdx.x * EPB;
    u64 rc[16];
    for (int i = tid; i < NB; i += 256) hist[i] = 0u;
    __syncthreads();
#pragma unroll
    for (int k = 0; k < 16; ++k) {
        size_t j = base + (size_t)k * 256 + tid;
        if (j < NE) {
            int dj = dst[j];
            rc[k] = (u64)(unsigned)src[j]
                  | ((u64)(unsigned)etype[j] << 17)
                  | ((u64)(unsigned)dj << 20);
            atomicAdd(&hist[dj >> BSH], 1u);
        } else rc[k] = ~0ull;
    }
    __syncthreads();
    for (int i = tid; i < NB; i += 256) {
        unsigned h = hist[i];
        curs[i] = h ? atomicAdd(cur + i, h) : 0u;
    }
    __syncthreads();
#pragma unroll
    for (int k = 0; k < 16; ++k) {
        if (rc[k] == ~0ull) continue;
        int dj = (int)(rc[k] >> 20);
        int b = dj >> BSH;
        unsigned pos = atomicAdd(&curs[b], 1u);
        unsigned eid = (unsigned)(base + (size_t)k * 256 + tid);
        part64[pos] = (rc[k] & 0xFFFFFull)
                    | ((u64)(unsigned)(dj & (BNODES - 1)) << 20)
                    | ((u64)eid << 27);
    }
}

// K3b: per-sub-bucket sum. Lane-per-edge; er + ee staged in LDS -> the ONLY divergent
// vector-memory per edge is the el gather (2 dwordx4) + coalesced u64 rec read.
// (Requests/edge: 7 in R4 -> ~3 here.)
__global__ __launch_bounds__(256) void k_bucket_sum(const u64* __restrict__ part64,
                                                    const unsigned* __restrict__ base,
                                                    const float* __restrict__ el,
                                                    const float* __restrict__ ers,
                                                    const float* __restrict__ ee_tab,
                                                    float* __restrict__ ers_out) {
    __shared__ float sbin[BNODES * 9];
    __shared__ float er_l[BNODES * 9];
    __shared__ float ee_l[NT * NH];
    int bs = blockIdx.x;
    int b = bs >> 2, c = bs & 3;     // SPLIT=4
    int tid = threadIdx.x;
    int n0 = b << BSH;
    int nn = NN - n0; if (nn > BNODES) nn = BNODES;

    for (int i = tid; i < BNODES * 9; i += 256) sbin[i] = 0.f;
    if (tid < NT * NH) ee_l[tid] = ee_tab[tid];
    for (int i = tid; i < nn * NH; i += 256) {
        int nl = i >> 3, hh = i & 7;
        er_l[nl * 9 + hh] = ers[(size_t)(n0 + nl) * 16 + hh];
    }
    __syncthreads();

    unsigned lo = base[b], hiB = base[b + 1];
    for (unsigned e = lo + (unsigned)(c * 256 + tid); e < hiB; e += 1024) {
        u64 rec = part64[e];
        int sj = (int)(rec & 0x1FFFFu);
        int et = (int)((rec >> 17) & 7u);
        int dl = (int)((rec >> 20) & (BNODES - 1));
        const float4* el4 = (const float4*)(el + (size_t)sj * 8);
        float4 la = el4[0], lb = el4[1];
        const float* erp = &er_l[dl * 9];
        const float* eep = &ee_l[et * 8];
        float* sb = &sbin[dl * 9];
        atomicAdd(&sb[0], __expf(fmaxf(la.x + erp[0] + eep[0], 0.f)));
        atomicAdd(&sb[1], __expf(fmaxf(la.y + erp[1] + eep[1], 0.f)));
        atomicAdd(&sb[2], __expf(fmaxf(la.z + erp[2] + eep[2], 0.f)));
        atomicAdd(&sb[3], __expf(fmaxf(la.w + erp[3] + eep[3], 0.f)));
        atomicAdd(&sb[4], __expf(fmaxf(lb.x + erp[4] + eep[4], 0.f)));
        atomicAdd(&sb[5], __expf(fmaxf(lb.y + erp[5] + eep[5], 0.f)));
        atomicAdd(&sb[6], __expf(fmaxf(lb.z + erp[6] + eep[6], 0.f)));
        atomicAdd(&sb[7], __expf(fmaxf(lb.w + erp[7] + eep[7], 0.f)));
    }
    __syncthreads();
    for (int i = tid; i < nn * NH; i += 256) {
        int nl = i >> 3, hh = i & 7;
        atomicAdd(&ers_out[(size_t)(n0 + nl) * 16 + 8 + hh], sbin[nl * 9 + hh]);
    }
}

// K4: bucket-ordered output pass (replaces edge-ordered k_edge_out).
// Per bucket: stage er + 1/s (st[128][17], pad 17 vs bank aliasing) and ee in LDS.
// Per edge: coalesced u64 rec, el gather x2, LDS reads, 8 exp, out[eid] scatter x2.
// (Requests/edge: ~10 in k_edge_out -> ~4.3; also deletes the 38MB src/dst/etype re-read.)
__global__ __launch_bounds__(256) void k_out(const u64* __restrict__ part64,
                                             const unsigned* __restrict__ base,
                                             const float* __restrict__ el,
                                             const float* __restrict__ ers,
                                             const float* __restrict__ ee_tab,
                                             float* __restrict__ out) {
    __shared__ float st[BNODES * 17];
    __shared__ float ee_l[NT * NH];
    int bs = blockIdx.x;
    int b = bs >> 2, c = bs & 3;     // SPLIT=4
    int tid = threadIdx.x;
    int n0 = b << BSH;
    int nn = NN - n0; if (nn > BNODES) nn = BNODES;

    if (tid < NT * NH) ee_l[tid] = ee_tab[tid];
    for (int i = tid; i < nn * 16; i += 256) {
        int nl = i >> 4, q = i & 15;
        float v = ers[(size_t)(n0 + nl) * 16 + q];
        st[nl * 17 + q] = (q < 8) ? v : 1.0f / v;   // cols 8..15 hold 1/s
    }
    __syncthreads();

    unsigned lo = base[b], hiB = base[b + 1];
    for (unsigned e = lo + (unsigned)(c * 256 + tid); e < hiB; e += 1024) {
        u64 rec = part64[e];
        int sj = (int)(rec & 0x1FFFFu);
        int et = (int)((rec >> 17) & 7u);
        int dl = (int)((rec >> 20) & (BNODES - 1));
        unsigned eid = (unsigned)(rec >> 27);
        const float4* el4 = (const float4*)(el + (size_t)sj * 8);
        float4 la = el4[0], lb = el4[1];
        const float* sp = &st[dl * 17];
        const float* eep = &ee_l[et * 8];
        float4 o0, o1;
        o0.x = __expf(fmaxf(la.x + sp[0] + eep[0], 0.f)) * sp[8];
        o0.y = __expf(fmaxf(la.y + sp[1] + eep[1], 0.f)) * sp[9];
        o0.z = __expf(fmaxf(la.z + sp[2] + eep[2], 0.f)) * sp[10];
        o0.w = __expf(fmaxf(la.w + sp[3] + eep[3], 0.f)) * sp[11];
        o1.x = __expf(fmaxf(lb.x + sp[4] + eep[4], 0.f)) * sp[12];
        o1.y = __expf(fmaxf(lb.y + sp[5] + eep[5], 0.f)) * sp[13];
        o1.z = __expf(fmaxf(lb.z + sp[6] + eep[6], 0.f)) * sp[14];
        o1.w = __expf(fmaxf(lb.w + sp[7] + eep[7], 0.f)) * sp[15];
        float4* o4 = (float4*)(out + (size_t)eid * 8);
        o4[0] = o0;
        o4[1] = o1;
    }
}

extern "C" void kernel_launch(void* const* d_in, const int* in_sizes, int n_in,
                              void* d_out, int out_size, void* d_ws, size_t ws_size,
                              hipStream_t stream) {
    const float* feat     = (const float*)d_in[0];
    const int*   etype    = (const int*)d_in[1];
    const int*   src      = (const int*)d_in[2];
    const int*   dst      = (const int*)d_in[3];
    const float* W_fc     = (const float*)d_in[4];
    const float* edge_emb = (const float*)d_in[5];
    const float* W_e      = (const float*)d_in[6];
    const float* attn_l   = (const float*)d_in[7];
    const float* attn_r   = (const float*)d_in[8];
    const float* attn_e   = (const float*)d_in[9];

    float*    ws      = (float*)d_ws;
    float*    At      = ws + WS_AT;
    float*    ee_tab  = ws + WS_EE;
    float*    el      = ws + WS_EL;
    float*    ers     = ws + WS_ERS;
    unsigned* ccnt    = (unsigned*)(ws + WS_CCNT);
    unsigned* basep   = (unsigned*)(ws + WS_BASE);
    unsigned* cur     = (unsigned*)(ws + WS_CUR);
    u64*      part64  = (u64*)(ws + WS_PART64);
    float*    out     = (float*)d_out;

    hipLaunchKernelGGL(k_prep_A, dim3(16), dim3(256), 0, stream, W_fc, attn_l, attn_r, At, ccnt);
    hipLaunchKernelGGL(k_prep_ee, dim3(1), dim3(512), 0, stream, edge_emb, W_e, attn_e, ee_tab);
    hipLaunchKernelGGL(k_node, dim3((NN + 255) / 256), dim3(256), 0, stream, feat, At, el, ers);
    hipLaunchKernelGGL(k_count, dim3((NE + EPB - 1) / EPB), dim3(256), 0, stream, dst, ccnt);
    hipLaunchKernelGGL(k_scan, dim3(1), dim3(256), 0, stream, ccnt, basep, cur);
    hipLaunchKernelGGL(k_partition, dim3((NE + EPB - 1) / EPB), dim3(256), 0, stream,
                       src, dst, etype, cur, part64);
    hipLaunchKernelGGL(k_bucket_sum, dim3(NB * SPLIT), dim3(256), 0, stream,
                       part64, basep, el, ers, ee_tab, ers);
    hipLaunchKernelGGL(k_out, dim3(NB * SPLIT), dim3(256), 0, stream,
                       part64, basep, el, ers, ee_tab, out);
}